// Round 1
// baseline (563.614 us; speedup 1.0000x reference)
//
#include <hip/hip_runtime.h>
#include <math.h>

#define N      96
#define NN     9216
#define LAT    256
#define ODIM   4656
#define CH     128      // k-chunks for GEMV partials
#define RPC    72       // rows per chunk (128*72 = 9216)
#define ITERS  50
#define MB     48       // mpm blocks (2 output columns each)
#define MT     192      // mpm threads per block
#define XPAD   100      // LDS row pad for x

// ---- workspace layout (float offsets) ----
#define WS_PART 0                       // [2][CH][LAT] = 65536
#define WS_ZMU  65536                   // 256
#define WS_ZLS  65792                   // 256
#define WS_Z    66048                   // 256
#define WS_KL   66304                   // 1
#define WS_BCEP 66308                   // 19
#define WS_OUTS 66336                   // 4656
#define WS_AOFT 71040                   // 9216 (Aoff transposed: [j][i])
#define WS_BOFF 80256                   // 9216 ([a][b])
#define WS_SDT  89472                   // 9216 (Sd transposed: [a][i])
#define WS_XB   98688                   // 2 x 9216 ping-pong
#define WS_PRT  117120                  // 2 x 48 sumsq partials

__device__ __forceinline__ int tri(int i, int j) {   // i <= j
    return i * N - i * (i - 1) / 2 + (j - i);
}

// ---- K1: partial GEMVs  h @ We11, h @ We12 ----
__global__ __launch_bounds__(256) void k1_gemv(const float* __restrict__ h,
                                               const float* __restrict__ W1,
                                               const float* __restrict__ W2,
                                               float* __restrict__ part) {
    __shared__ float hs[RPC];
    int t = threadIdx.x, c = blockIdx.x;
    int k0 = c * RPC;
    if (t < RPC) hs[t] = h[k0 + t];
    __syncthreads();
    float a1 = 0.f, a2 = 0.f;
    #pragma unroll 4
    for (int kk = 0; kk < RPC; ++kk) {
        float hv = hs[kk];
        a1 = fmaf(hv, W1[(k0 + kk) * LAT + t], a1);
        a2 = fmaf(hv, W2[(k0 + kk) * LAT + t], a2);
    }
    part[c * LAT + t]            = a1;
    part[(CH + c) * LAT + t]     = a2;
}

// ---- K2a: reduce partials -> z_mu, z_ls ----
__global__ __launch_bounds__(256) void k2a_reduce(const float* __restrict__ part,
                                                  const float* __restrict__ be11,
                                                  const float* __restrict__ be12,
                                                  float* __restrict__ zmu,
                                                  float* __restrict__ zls) {
    int w = blockIdx.x, o = threadIdx.x;
    const float* p = part + w * CH * LAT + o;
    float acc = 0.f;
    #pragma unroll 8
    for (int c = 0; c < CH; ++c) acc += p[c * LAT];
    if (w == 0) zmu[o] = acc + be11[o];
    else        zls[o] = acc + be12[o];
}

// ---- K2b: z = eps*exp(0.5 ls) + mu ; KL ----
__global__ __launch_bounds__(256) void k2b_z_kl(const float* __restrict__ zmu_a,
                                                const float* __restrict__ zls_a,
                                                const float* __restrict__ eps,
                                                float* __restrict__ z,
                                                float* __restrict__ klp) {
    __shared__ float red[LAT];
    int o = threadIdx.x;
    float mu = zmu_a[o], ls = zls_a[o];
    z[o] = eps[o] * expf(0.5f * ls) + mu;
    red[o] = 1.0f + ls - mu * mu - expf(ls);
    __syncthreads();
    for (int s = 128; s > 0; s >>= 1) {
        if (o < s) red[o] += red[o + s];
        __syncthreads();
    }
    if (o == 0) klp[0] = -0.5f * red[0] / 9216.0f;
}

// ---- K3: hidden = relu(z@Wd1+bd1); out = sigmoid(hidden@Wd2+bd2); BCE partials ----
__device__ __forceinline__ int tri_row(int o) {
    int i = (int)floorf((193.0f - sqrtf((float)(37249 - 8 * o))) * 0.5f);
    i = max(0, min(95, i));
    while ((i + 1) * N - (i + 1) * i / 2 <= o) ++i;
    while (i * N - i * (i - 1) / 2 > o) --i;
    return i;
}

__global__ __launch_bounds__(256) void k3_dec(const float* __restrict__ z,
                                              const float* __restrict__ Wd1,
                                              const float* __restrict__ bd1,
                                              const float* __restrict__ Wd2,
                                              const float* __restrict__ bd2,
                                              const float* __restrict__ adj,
                                              float* __restrict__ outs,
                                              float* __restrict__ bcep) {
    __shared__ float zi[LAT];
    __shared__ float hid[LAT];
    __shared__ float red[256];
    int t = threadIdx.x;
    zi[t] = z[t];
    __syncthreads();
    float acc = 0.f;
    #pragma unroll 8
    for (int k = 0; k < LAT; ++k) acc = fmaf(zi[k], Wd1[k * LAT + t], acc);
    hid[t] = fmaxf(acc + bd1[t], 0.f);
    __syncthreads();
    int o = blockIdx.x * 256 + t;
    float term = 0.f;
    if (o < ODIM) {
        float a2 = 0.f;
        #pragma unroll 8
        for (int k = 0; k < LAT; ++k) a2 = fmaf(hid[k], Wd2[k * ODIM + o], a2);
        float y = a2 + bd2[o];
        float s = 1.0f / (1.0f + expf(-y));
        outs[o] = s;
        int i = tri_row(o);
        int j = i + (o - (i * N - i * (i - 1) / 2));
        float inp = adj[i * N + j];
        float li = fmaxf(logf(inp), -100.0f);
        float l1 = fmaxf(log1pf(-inp), -100.0f);
        term = s * li + (1.0f - s) * l1;
    }
    red[t] = term;
    __syncthreads();
    for (int s = 128; s > 0; s >>= 1) {
        if (t < s) red[t] += red[t + s];
        __syncthreads();
    }
    if (t == 0) bcep[blockIdx.x] = red[0];
}

// ---- K4: build AoffT, Boff, SdT, x0, norm partial init ----
__global__ __launch_bounds__(256) void k4_build(const float* __restrict__ adj,
                                                const float* __restrict__ outs,
                                                float* __restrict__ AoffT,
                                                float* __restrict__ Boff,
                                                float* __restrict__ SdT,
                                                float* __restrict__ xb0,
                                                float* __restrict__ prt) {
    __shared__ float ds[N], drs[N], ft[N], ftr[N];
    int t = threadIdx.x;
    if (t < N) {
        ds[t]  = adj[t * N + t];
        drs[t] = outs[tri(t, t)];
        float s1 = 0.f, s2 = 0.f;
        for (int b = 0; b < N; ++b) {
            s1 += adj[t * N + b];
            int lo = min(t, b), hi = max(t, b);
            s2 += outs[tri(lo, hi)];
        }
        ft[t] = s1; ftr[t] = s2;
    }
    __syncthreads();
    for (int f = t; f < NN; f += 256) {
        int i = f / N, j = f % N;
        float av = (i == j) ? 0.f : (adj[f] * ds[i]) * ds[j];
        AoffT[j * N + i] = av;
        int lo = min(i, j), hi = max(i, j);
        float rec = outs[tri(lo, hi)];
        Boff[f] = (i == j) ? 0.f : (rec * drs[i]) * drs[j];
        // f = a*N + i2 for SdT
        int a = i, i2 = j;
        SdT[f] = (ds[i2] * drs[a]) * (1.0f / (fabsf(ft[i2] - ftr[a]) + 1.0f));
        xb0[f] = (float)(1.0 / 96.0);
    }
    if (t < MB) prt[t] = (t == 0) ? 1.0f : 0.f;
}

// ---- K5: one MPM iteration.  x_new = x*Sd + Aoff @ (max_b Boff[a,b]*x[j,b]) ----
__global__ __launch_bounds__(MT) void k5_mpm(const float* __restrict__ xin,
                                             float* __restrict__ xout,
                                             const float* __restrict__ pin,
                                             float* __restrict__ pout,
                                             const float* __restrict__ AoffT,
                                             const float* __restrict__ Boff,
                                             const float* __restrict__ SdT) {
    __shared__ float xn[N][XPAD];
    __shared__ float Brow[2][N];
    __shared__ float Scol[2][N];
    __shared__ float Mv[2][N];
    __shared__ float red[MT];
    __shared__ float s_inv;
    int t = threadIdx.x;
    int a0 = blockIdx.x * 2;
    int jj = t % N, al = t / N;       // task index: (row j / i, column half)

    if (t < MB) red[t] = pin[t];
    __syncthreads();
    if (t == 0) {
        float s = 0.f;
        for (int c = 0; c < MB; ++c) s += red[c];
        s_inv = 1.0f / sqrtf(s);
    }
    Brow[al][jj] = Boff[(a0 + al) * N + jj];
    Scol[al][jj] = SdT[(a0 + al) * N + jj];
    __syncthreads();
    float inv = s_inv;

    // stage normalized x into LDS
    for (int q = t; q < NN / 4; q += MT) {
        float4 v = ((const float4*)xin)[q];
        int f = q * 4; int i = f / N; int b = f % N;
        v.x *= inv; v.y *= inv; v.z *= inv; v.w *= inv;
        *(float4*)&xn[i][b] = v;
    }
    __syncthreads();

    // phase B: M[j,a] = max_b Boff[a,b] * xn[j,b]
    float m = 0.f;
    #pragma unroll
    for (int bq = 0; bq < N / 4; ++bq) {
        float4 xv = *(const float4*)&xn[jj][bq * 4];
        m = fmaxf(m, Brow[al][bq * 4 + 0] * xv.x);
        m = fmaxf(m, Brow[al][bq * 4 + 1] * xv.y);
        m = fmaxf(m, Brow[al][bq * 4 + 2] * xv.z);
        m = fmaxf(m, Brow[al][bq * 4 + 3] * xv.w);
    }
    Mv[al][jj] = m;
    __syncthreads();

    // phase C: x_new[i,a] = xn[i,a]*Sd[i,a] + sum_j AoffT[j,i]*M[j,a]
    float acc = xn[jj][a0 + al] * Scol[al][jj];
    #pragma unroll 8
    for (int j = 0; j < N; ++j)
        acc = fmaf(AoffT[j * N + jj], Mv[al][j], acc);
    xout[jj * N + (a0 + al)] = acc;

    // block sumsq partial
    red[t] = acc * acc;
    __syncthreads();
    if (t < 96) red[t] += red[t + 96]; __syncthreads();
    if (t < 48) red[t] += red[t + 48]; __syncthreads();
    if (t < 24) red[t] += red[t + 24]; __syncthreads();
    if (t < 12) red[t] += red[t + 12]; __syncthreads();
    if (t < 6)  red[t] += red[t + 6];  __syncthreads();
    if (t == 0) pout[blockIdx.x] = red[0] + red[1] + red[2] + red[3] + red[4] + red[5];
}

// ---- K6: final normalize + loss ----
__global__ __launch_bounds__(256) void k6_final(const float* __restrict__ xb0,
                                                const float* __restrict__ prt,
                                                const float* __restrict__ bcep,
                                                const float* __restrict__ klp,
                                                float* __restrict__ out) {
    __shared__ float nrm;
    int t = threadIdx.x;
    if (t == 0) {
        float s = 0.f;
        for (int c = 0; c < MB; ++c) s += prt[c];
        nrm = sqrtf(s);
        float bce = 0.f;
        for (int b = 0; b < 19; ++b) bce += bcep[b];
        out[0] = -(bce / 4656.0f) + klp[0];
    }
    __syncthreads();
    float nv = nrm;
    for (int f = t; f < NN; f += 256) out[1 + f] = xb0[f] / nv;
}

extern "C" void kernel_launch(void* const* d_in, const int* in_sizes, int n_in,
                              void* d_out, int out_size, void* d_ws, size_t ws_size,
                              hipStream_t stream) {
    const float* inf  = (const float*)d_in[0];
    const float* adj  = (const float*)d_in[1];
    const float* eps  = (const float*)d_in[2];
    const float* We11 = (const float*)d_in[3];
    const float* be11 = (const float*)d_in[4];
    const float* We12 = (const float*)d_in[5];
    const float* be12 = (const float*)d_in[6];
    const float* Wd1  = (const float*)d_in[7];
    const float* bd1  = (const float*)d_in[8];
    const float* Wd2  = (const float*)d_in[9];
    const float* bd2  = (const float*)d_in[10];
    float* ws  = (float*)d_ws;
    float* out = (float*)d_out;

    k1_gemv  <<<CH, 256, 0, stream>>>(inf, We11, We12, ws + WS_PART);
    k2a_reduce<<<2, 256, 0, stream>>>(ws + WS_PART, be11, be12, ws + WS_ZMU, ws + WS_ZLS);
    k2b_z_kl <<<1, 256, 0, stream>>>(ws + WS_ZMU, ws + WS_ZLS, eps, ws + WS_Z, ws + WS_KL);
    k3_dec   <<<19, 256, 0, stream>>>(ws + WS_Z, Wd1, bd1, Wd2, bd2, adj,
                                      ws + WS_OUTS, ws + WS_BCEP);
    k4_build <<<1, 256, 0, stream>>>(adj, ws + WS_OUTS, ws + WS_AOFT, ws + WS_BOFF,
                                     ws + WS_SDT, ws + WS_XB, ws + WS_PRT);
    for (int it = 0; it < ITERS; ++it) {
        const float* xi = ws + WS_XB + (it & 1) * NN;
        float*       xo = ws + WS_XB + ((it + 1) & 1) * NN;
        const float* pi = ws + WS_PRT + (it & 1) * MB;
        float*       po = ws + WS_PRT + ((it + 1) & 1) * MB;
        k5_mpm<<<MB, MT, 0, stream>>>(xi, xo, pi, po,
                                      ws + WS_AOFT, ws + WS_BOFF, ws + WS_SDT);
    }
    k6_final<<<1, 256, 0, stream>>>(ws + WS_XB, ws + WS_PRT, ws + WS_BCEP,
                                    ws + WS_KL, out);
}